// Round 2
// baseline (494.184 us; speedup 1.0000x reference)
//
#include <hip/hip_runtime.h>

// Direct 3x3 conv, NCHW fp32. N=32, C_IN=3, H=W=224, C_OUT=64, stride 1, pad 1.
// 4 consecutive output pixels (along W) per thread; dynamic loop over all 64
// c_out with wave-uniform weights (scalar loads). float4 coalesced stores.

#define N_IMG 32
#define C_IN 3
#define H_ 224
#define W_ 224
#define C_OUT 64
#define NPIX (H_ * W_)      // 50176 = 224*224; 50176/4 = 12544 = 49*256 threads/img
#define PIX_PER_THREAD 4

__global__ __launch_bounds__(256) void conv3x3_p4(
    const float* __restrict__ x,      // [N, C_IN, H, W]
    const float* __restrict__ wgt,    // [C_OUT, C_IN, 3, 3]
    const float* __restrict__ bias,   // [C_OUT]
    float* __restrict__ out)          // [N, C_OUT, H, W]
{
    const int t  = blockIdx.x * 256 + threadIdx.x;   // thread index within image
    const int p0 = t * PIX_PER_THREAD;               // first pixel (multiple of 4)
    const int n  = blockIdx.y;
    const int h  = p0 / W_;
    const int w0 = p0 - h * W_;                      // w0 % 4 == 0, w0 <= 220

    const float* xn = x + (size_t)n * C_IN * NPIX;
    const bool wl = (w0 > 0);            // left-edge in-bounds?
    const bool wr = (w0 + 4 < W_);       // right-edge in-bounds?

    // Input window: 9 rows (ci x dh) of 6 consecutive values [w0-1 .. w0+4].
    float in_v[9][6];
#pragma unroll
    for (int ci = 0; ci < 3; ++ci) {
#pragma unroll
        for (int dh = 0; dh < 3; ++dh) {
            const int r  = ci * 3 + dh;
            const int hh = h + dh - 1;
            const bool hok = (unsigned)hh < (unsigned)H_;
            const float* rowp = xn + ci * NPIX + hh * W_;
            in_v[r][0] = (hok && wl) ? rowp[w0 - 1] : 0.0f;
            if (hok) {
                const float4 m = *(const float4*)(rowp + w0);   // 16B aligned
                in_v[r][1] = m.x; in_v[r][2] = m.y;
                in_v[r][3] = m.z; in_v[r][4] = m.w;
            } else {
                in_v[r][1] = 0.0f; in_v[r][2] = 0.0f;
                in_v[r][3] = 0.0f; in_v[r][4] = 0.0f;
            }
            in_v[r][5] = (hok && wr) ? rowp[w0 + 4] : 0.0f;
        }
    }

    float* outp = out + (size_t)n * C_OUT * NPIX + p0;
#pragma unroll 2
    for (int c = 0; c < C_OUT; ++c) {
        const float* wp = wgt + c * 27;      // wave-uniform -> scalar loads
        const float b = bias[c];
        float a0 = b, a1 = b, a2 = b, a3 = b;
#pragma unroll
        for (int r = 0; r < 9; ++r) {
#pragma unroll
            for (int dw = 0; dw < 3; ++dw) {
                const float wv = wp[r * 3 + dw];
                a0 = fmaf(in_v[r][dw + 0], wv, a0);
                a1 = fmaf(in_v[r][dw + 1], wv, a1);
                a2 = fmaf(in_v[r][dw + 2], wv, a2);
                a3 = fmaf(in_v[r][dw + 3], wv, a3);
            }
        }
        const float4 o = make_float4(a0, a1, a2, a3);
        *(float4*)(outp + (size_t)c * NPIX) = o;    // 1 KB/wave coalesced store
    }
}

extern "C" void kernel_launch(void* const* d_in, const int* in_sizes, int n_in,
                              void* d_out, int out_size, void* d_ws, size_t ws_size,
                              hipStream_t stream) {
    const float* x    = (const float*)d_in[0];
    const float* wgt  = (const float*)d_in[1];
    const float* bias = (const float*)d_in[2];
    float* out = (float*)d_out;

    dim3 grid(NPIX / (256 * PIX_PER_THREAD), N_IMG);   // 49 x 32 blocks
    dim3 block(256);
    conv3x3_p4<<<grid, block, 0, stream>>>(x, wgt, bias, out);
}